// Round 19
// baseline (636.306 us; speedup 1.0000x reference)
//
#include <hip/hip_runtime.h>

#define PI_D 3.14159265358979323846

constexpr int S_L20 = 12341;  // sum_{l<=20} (2l+1)^2
constexpr int S_L10 = 1771;
constexpr int S_L5  = 286;
constexpr int C_L20 = 441;    // (20+1)^2

typedef float f4 __attribute__((ext_vector_type(4)));
typedef float f2 __attribute__((ext_vector_type(2)));
template<int W> struct VW;
template<> struct VW<4> { using T = f4; };
template<> struct VW<2> { using T = f2; };

__host__ __device__ __forceinline__ int loff(int l) { return l*(4*l*l-1)/3; }

__device__ __forceinline__ int isqrt_dev(int c) {
  int l = (int)sqrtf((float)c);
  while ((l+1)*(l+1) <= c) ++l;
  while (l*l > c) --l;
  return l;
}

// small Wigner-d d^l_{mp,m}(beta); cpw/spw are power tables of cos(beta/2), sin(beta/2)
__device__ double d_small(int l, int mp, int m, const double* cpw, const double* spw, const double* fact) {
  double pref = sqrt(fact[l+mp]*fact[l-mp]*fact[l+m]*fact[l-m]);
  int k0 = max(0, m-mp), k1 = min(l+m, l-mp);
  double val = 0.0;
  for (int k = k0; k <= k1; ++k) {
    double den = fact[l+m-k]*fact[k]*fact[mp-m+k]*fact[l-mp-k];
    double t = (pref/den)*cpw[2*l+m-mp-2*k]*spw[mp-m+2*k];
    val += ((mp-m+k)&1) ? -t : t;
  }
  return val;
}

// real-basis Wigner-d element, row ap, col bp (signed, in [-l,l]).
__device__ double dr_elem(int l, int ap, int bp, const double* cpw, const double* spw, const double* fact) {
  const double IR2 = 0.70710678118654752440;
  if (ap == 0 && bp == 0) return d_small(l,0,0,cpw,spw,fact);
  if (bp == 0) {
    if (ap < 0) return 0.0;
    double sp = (ap&1)? -1.0: 1.0;
    return IR2*(d_small(l,-ap,0,cpw,spw,fact) + sp*d_small(l,ap,0,cpw,spw,fact));
  }
  if (ap == 0) {
    if (bp < 0) return 0.0;
    double sm = (bp&1)? -1.0: 1.0;
    return IR2*(d_small(l,0,-bp,cpw,spw,fact) + sm*d_small(l,0,bp,cpw,spw,fact));
  }
  if (ap > 0 && bp > 0) {
    double sp = (ap&1)?-1.0:1.0, sm = (bp&1)?-1.0:1.0;
    return 0.5*(d_small(l,-ap,-bp,cpw,spw,fact) + sm*d_small(l,-ap,bp,cpw,spw,fact)
              + sp*d_small(l,ap,-bp,cpw,spw,fact) + sp*sm*d_small(l,ap,bp,cpw,spw,fact));
  }
  if (ap < 0 && bp < 0) {
    int mp = -ap, m = -bp;
    double sp = (mp&1)?-1.0:1.0, sm = (m&1)?-1.0:1.0;
    return 0.5*(d_small(l,-mp,-m,cpw,spw,fact) - sm*d_small(l,-mp,m,cpw,spw,fact)
              - sp*d_small(l,mp,-m,cpw,spw,fact) + sp*sm*d_small(l,mp,m,cpw,spw,fact));
  }
  return 0.0;
}

// beta of point p: mode 0: (p+0.5)*pi/gridn ; mode 1: so3 near-identity ; mode 2: s2 near-identity
__device__ double beta_of(int mode, int p, int gridn) {
  if (mode == 0) return (p + 0.5) * (PI_D / gridn);
  if (mode == 1) return (double)(((p >> 3) % 3) + 1) * (PI_D / 24.0);
  return (double)((p % 3) + 1) * (PI_D / 24.0);
}

// ALL small constant tables in ONE launch: dr tables + drc tables + trig + luts.
__global__ __launch_bounds__(256) void k_tables(float* dr20g1, float* drK2, float* dr10g1, float* dr10g2,
                                                float* drK3, float* dr5g2, float* dr5g3, float* dr0g3,
                                                float* drc60, float* drc24,
                                                float* t1c, float* t1s, float* t2c, float* t2s,
                                                float* t3c, float* t3s,
                                                unsigned* lut10, unsigned* lut5) {
  __shared__ double cpw[44], spw[44], fact[44];
  int b = blockIdx.x;
  int tid = threadIdx.x;
  if (b < 846) {
    // ---- full real Wigner-d tables ----
    float* out; int lmax, S, mode, gridn, p, chunk;
    if (b < 260)      { out=dr20g1; lmax=20; S=S_L20; mode=0; gridn=20; p=b/13;        chunk=b%13; }
    else if (b < 596) { int i=b-260; out=drK2;   lmax=10; S=S_L10; mode=1; gridn=0;  p=i/2; chunk=i%2; }
    else if (b < 636) { int i=b-596; out=dr10g1; lmax=10; S=S_L10; mode=0; gridn=20; p=i/2; chunk=i%2; }
    else if (b < 656) { int i=b-636; out=dr10g2; lmax=10; S=S_L10; mode=0; gridn=10; p=i/2; chunk=i%2; }
    else if (b < 824) { int i=b-656; out=drK3;   lmax=5;  S=S_L5;  mode=1; gridn=0;  p=i;   chunk=0; }
    else if (b < 834) { int i=b-824; out=dr5g2;  lmax=5;  S=S_L5;  mode=0; gridn=10; p=i;   chunk=0; }
    else if (b < 840) { int i=b-834; out=dr5g3;  lmax=5;  S=S_L5;  mode=0; gridn=6;  p=i;   chunk=0; }
    else              { int i=b-840; out=dr0g3;  lmax=0;  S=1;     mode=0; gridn=6;  p=i;   chunk=0; }
    double beta_ = beta_of(mode, p, gridn);
    if (tid == 0) {
      double cb_ = cos(beta_*0.5), sb_ = sin(beta_*0.5);
      cpw[0]=1.0; spw[0]=1.0; fact[0]=1.0;
      for (int i_=1;i_<44;++i_){cpw[i_]=cpw[i_-1]*cb_; spw[i_]=spw[i_-1]*sb_; fact[i_]=fact[i_-1]*(double)i_;}
    }
    __syncthreads();
    int base = chunk*1024;
    int end = min(S, base + 1024);
    for (int t = base + tid; t < end; t += 256) {
      int l = 0; while (l < lmax && t >= loff(l+1)) ++l;
      int j = t - loff(l), d = 2*l+1;
      int a = j/d, bb = j%d;
      double v = dr_elem(l, a-l, bb-l, cpw, spw, fact) * sqrt(2.0*l+1.0);
      out[(size_t)p*S + t] = (float)v;
    }
  } else if (b < 930) {
    // ---- m=0 column tables ----
    int bb = b - 846;
    float* out; int mode, gridn, p;
    if (bb < 60) { out = drc60; mode = 0; gridn = 60; p = bb; }
    else         { out = drc24; mode = 2; gridn = 0;  p = bb - 60; }
    double beta_ = beta_of(mode, p, gridn);
    if (tid == 0) {
      double cb_ = cos(beta_*0.5), sb_ = sin(beta_*0.5);
      cpw[0]=1.0; spw[0]=1.0; fact[0]=1.0;
      for (int i_=1;i_<44;++i_){cpw[i_]=cpw[i_-1]*cb_; spw[i_]=spw[i_-1]*sb_; fact[i_]=fact[i_-1]*(double)i_;}
    }
    __syncthreads();
    for (int t = tid; t < C_L20; t += 256) {
      int l = isqrt_dev(t);
      int u = t - l*l - l;
      double v;
      if (u < 0) v = 0.0;
      else if (u == 0) v = d_small(l,0,0,cpw,spw,fact);
      else {
        double sp = (u&1)? -1.0: 1.0;
        v = 0.70710678118654752440*(d_small(l,-u,0,cpw,spw,fact) + sp*d_small(l,u,0,cpw,spw,fact));
      }
      out[(size_t)p*C_L20 + t] = (float)(v * sqrt(2.0*l+1.0));
    }
  } else if (b < 933) {
    // ---- trig tables ----
    int t = (b - 930)*256 + tid;
    if (t < 420) {
      int k = t/20, ig = t%20;
      double ang = (double)k*(double)ig*(2.0*PI_D/20.0);
      t1c[t] = (float)cos(ang); t1s[t] = (float)sin(ang);
    } else if (t < 530) {
      int i = t-420, k = i/10, ig = i%10;
      double ang = (double)k*(double)ig*(2.0*PI_D/10.0);
      t2c[i] = (float)cos(ang); t2s[i] = (float)sin(ang);
    } else if (t < 566) {
      int i = t-530, k = i/6, ig = i%6;
      double ang = (double)k*(double)ig*(2.0*PI_D/6.0);
      t3c[i] = (float)cos(ang); t3s[i] = (float)sin(ang);
    }
  } else {
    // ---- s->(l,u,v) LUTs ----
    int t = (b - 933)*256 + tid;
    unsigned* lut; int s, lmax;
    if (t < S_L10) { lut = lut10; s = t; lmax = 10; }
    else if (t < S_L10 + S_L5) { lut = lut5; s = t - S_L10; lmax = 5; }
    else return;
    int l = 0; while (l < lmax && s >= loff(l+1)) ++l;
    int j = s - loff(l), d = 2*l+1;
    int u = j/d, v = j - u*d;
    lut[s] = (unsigned)l | ((unsigned)u<<8) | ((unsigned)v<<16);
  }
}

// psi1 + both D_K tables + coeff (FS2 computed on the fly) in ONE launch.
__global__ __launch_bounds__(256) void k_tab2(const float* __restrict__ drc24, const float* __restrict__ w1,
                                              float* __restrict__ psi1,
                                              const float* __restrict__ drk2, float* __restrict__ DK2,
                                              const float* __restrict__ drk3, float* __restrict__ DK3,
                                              const float* __restrict__ drc60, const float* __restrict__ x,
                                              float* __restrict__ coeff) {
  __shared__ float red[2048];
  __shared__ float cu[60], su[60], sbq[60];
  int b = blockIdx.x, tid = threadIdx.x;
  if (b < 111) {
    // ---- psi1 ----
    int e = b*256 + tid;
    if (e >= 64*441) return;
    int o = e / 441, c = e % 441;
    int l = isqrt_dev(c);
    int u = c - l*l - l;
    float acc = 0.f;
    for (int p = 0; p < 24; ++p) {
      double alpha = (double)(p/3)*(PI_D/4.0);
      double y = cos((double)u*alpha)*(double)drc24[p*441+c] + sin((double)u*alpha)*(double)drc24[p*441 + (c-2*u)];
      acc += (float)y * w1[o*24 + p];
    }
    psi1[e] = acc * 0.20412414523193150818f;
  } else if (b < 1463) {
    // ---- both D_K tables (padded strides) ----
    int e0 = (b - 111)*256 + tid;
    const float* drk; float* DK; int S, NP, lmax, e;
    if (e0 < 168*1772) { drk = drk2; DK = DK2; S = S_L10; NP = 1772; lmax = 10; e = e0; }
    else { e = e0 - 168*1772; if (e >= 168*288) return; drk = drk3; DK = DK3; S = S_L5; NP = 288; lmax = 5; }
    int n = e / NP, idx = e % NP;
    if (idx >= S) { DK[e] = 0.f; return; }
    int l = 0; while (l < lmax && idx >= loff(l+1)) ++l;
    int j = idx - loff(l), d = 2*l+1;
    int iu = j/d, im = j%d;
    int u = iu - l, m = im - l;
    int i3 = n/24, k3 = n%8;
    double alpha = (double)i3*(2.0*PI_D/7.0);
    double gamma = (-2.0*PI_D + (double)k3*(4.0*PI_D/7.0)) - alpha;
    const float* drb = drk + (size_t)n*S + loff(l);
    double d_um   = drb[iu*d+im];
    double d_umn  = drb[iu*d + (d-1-im)];
    double d_unm  = drb[(d-1-iu)*d + im];
    double d_unmn = drb[(d-1-iu)*d + (d-1-im)];
    double cA = cos((double)u*alpha), sA = sin((double)u*alpha);
    double cG = cos((double)m*gamma), sG = sin((double)m*gamma);
    DK[e] = (float)(cA*(cG*d_um - sG*d_umn) + sA*(cG*d_unm - sG*d_unmn));
  } else {
    // ---- coeff[b][c] with inline FS2 (per-block trig caches) ----
    int c = b - 1463;
    int l = isqrt_dev(c);
    int u = c - l*l - l;
    int cneg = c - 2*u;
    if (tid < 60) {
      double alpha = (double)tid*(2.0*PI_D/60.0);
      double beta  = ((double)tid + 0.5)*(PI_D/60.0);
      cu[tid]  = (float)cos((double)u*alpha);
      su[tid]  = (float)sin((double)u*alpha);
      sbq[tid] = (float)(sin(beta)*PI_D/(2.0*60.0*60.0));
    }
    __syncthreads();
    float acc[8] = {};
    for (int k = tid; k < 3600; k += 256) {
      int ia = k / 60, ib2 = k % 60;
      double val = (double)cu[ia]*(double)drc60[ib2*441 + c] + (double)su[ia]*(double)drc60[ib2*441 + cneg];
      float w = (float)(val) * sbq[ib2];
#pragma unroll
      for (int bb = 0; bb < 8; ++bb) acc[bb] += w * x[bb*3600 + k];
    }
#pragma unroll
    for (int bb = 0; bb < 8; ++bb) red[bb*256 + tid] = acc[bb];
    __syncthreads();
    for (int s = 128; s > 0; s >>= 1) {
      if (tid < s) {
#pragma unroll
        for (int bb = 0; bb < 8; ++bb) red[bb*256 + tid] += red[bb*256 + tid + s];
      }
      __syncthreads();
    }
    if (tid < 8) coeff[tid*441 + c] = red[tid*256];
  }
}

// ping-pong LDS 64x64 GEMM body, K-step 16, f4 staging, packed-psi epilogue.
__device__ __forceinline__ void gemm_body(const float* __restrict__ A, const float* __restrict__ B,
                                          const unsigned* __restrict__ lut, float* __restrict__ C,
                                          int M, int N, int NP, int K, int FO, int tm, int tn, float alpha,
                                          float (*As)[16][68], float (*Bs)[16][68], int tid) {
  int ty = tid/16, tx = tid%16;
  int arr = tid>>2, akq = (tid&3)*4;
  int bkk = tid>>4, bcq = (tid&15)*4;
  const float* Arow = A + (size_t)(tm + arr)*K;
  const f4 FZ = 0.f;
  float acc[4][4] = {};
  f4 ra, rb;
#define LOADC(k0)                                                        \
  if ((k0) + 16 <= K) {                                                  \
    ra = *(const f4*)&Arow[(k0) + akq];                                  \
    rb = *(const f4*)&B[(size_t)((k0) + bkk)*NP + tn + bcq];             \
  } else {                                                               \
    _Pragma("unroll")                                                    \
    for (int jj = 0; jj < 4; ++jj) {                                     \
      int k = (k0) + akq + jj;                                           \
      ra[jj] = (k < K) ? Arow[k] : 0.f;                                  \
    }                                                                    \
    int k2 = (k0) + bkk;                                                 \
    rb = (k2 < K) ? *(const f4*)&B[(size_t)k2*NP + tn + bcq] : FZ;       \
  }
#define STOREC(b)                                                        \
  {                                                                      \
    _Pragma("unroll")                                                    \
    for (int jj = 0; jj < 4; ++jj) As[b][akq+jj][arr] = ra[jj];          \
    *(f4*)&Bs[b][bkk][bcq] = rb;                                         \
  }
  LOADC(0);
  STOREC(0);
  __syncthreads();
  int cur = 0;
  for (int k0 = 0; k0 < K; k0 += 16) {
    bool nxt = (k0 + 16) < K;
    if (nxt) { LOADC(k0 + 16); }
#pragma unroll
    for (int kk = 0; kk < 16; ++kk) {
      f4 av = *(const f4*)&As[cur][kk][ty*4];
      f4 bv = *(const f4*)&Bs[cur][kk][tx*4];
#pragma unroll
      for (int q = 0; q < 4; ++q)
#pragma unroll
        for (int r2 = 0; r2 < 4; ++r2) acc[q][r2] += av[q]*bv[r2];
    }
    if (nxt) { STOREC(cur ^ 1); __syncthreads(); cur ^= 1; }
  }
#undef LOADC
#undef STOREC
  for (int q = 0; q < 4; ++q) {
    int r = tm + ty*4 + q; if (r >= M) continue;
    int i = r / FO, o = r - i*FO;
    for (int r2 = 0; r2 < 4; ++r2) {
      int c = tn + tx*4 + r2; if (c >= N) continue;
      unsigned e = lut[c];
      int l = e & 255, u = (e>>8)&255, v = (e>>16)&255;
      int d = 2*l+1;
      C[(size_t)M*loff(l) + (size_t)(i*d+u)*(FO*d) + o*d + v] = alpha*acc[q][r2];
    }
  }
}

// RANK-1 synthesis body (L=20, NG=20, F=64, BS=256), batched 2f x 1b (2 combos).
__device__ void syn1b_body(const float* __restrict__ psi1, const float* __restrict__ coeff,
                           const float* __restrict__ drg,
                           const float* __restrict__ gtck, const float* __restrict__ gtsk,
                           float* __restrict__ fw, int ib, int f0, int b0, int tid,
                           float* PF, float* Q1F, float* Q2F, float* Q3F,
                           float* uni, float* tck, float* tsk) {
  constexpr int L = 20, NG = 20, F = 64, BS = 256;
  constexpr int LH = L+1;
  constexpr int LH2 = LH*LH;
  constexpr int S = S_L20;
  constexpr int IGB = 4;
  constexpr int NGB = NG / IGB;
  float* psi_s  = uni;              // 2 x 441
  float* coef_s = uni + 2*C_L20;    // 1 x 441
  float* Rc = uni;                  // overlay after stage A
  float* Rs = uni + LH*NG;
  for (int t = tid; t < C_L20; t += BS) {
    psi_s[t]          = psi1[f0*C_L20 + t];
    psi_s[C_L20 + t]  = psi1[(f0+1)*C_L20 + t];
    coef_s[t]         = coeff[b0*C_L20 + t];
  }
  for (int t = tid; t < LH*NG; t += BS) { tck[t] = gtck[t]; tsk[t] = gtsk[t]; }
  __syncthreads();
  const float* drb = drg + (size_t)ib*S;
  for (int t = tid; t < LH2; t += BS) {
    int i = t / LH, j = t % LH;
    int lmin = max(i, j);
    float P[2] = {}, Q1[2] = {}, Q2[2] = {}, Q3[2] = {};
    int d = 2*lmin+1;
    int j2 = 2*j;
    int drip = loff(lmin) + (lmin+i)*d + (lmin-j);
    int drim = loff(lmin) + (lmin-i)*d + (lmin-j);
    int hA = lmin*lmin + lmin + i;
    int hB = lmin*lmin + lmin - i;
    int hM = lmin*lmin + lmin - j;
    int hMp = lmin*lmin + lmin + j;
    for (int l = lmin; l <= L; ++l) {
      float ap_ = drb[drip], app = drb[drip + j2];
      float am_ = 0.f, amp = 0.f;
      if (i > 0) { am_ = drb[drim]; amp = drb[drim + j2]; }
      float hm = coef_s[hM], hmn = coef_s[hMp];
      float eP = ap_*hm + app*hmn, oP = app*hm - ap_*hmn;
      float eM = am_*hm + amp*hmn, oM = amp*hm - am_*hmn;
#pragma unroll
      for (int cf = 0; cf < 2; ++cf) {
        float ha = psi_s[cf*C_L20 + hA], hb = psi_s[cf*C_L20 + hB];
        P[cf]  += ha*eP + hb*eM;
        Q1[cf] += ha*oP + hb*oM;
        Q2[cf] += hb*eP - ha*eM;
        Q3[cf] += hb*oP - ha*oM;
      }
      drip += d*d + d + 2*(l+i) + 3;
      drim += d*d + d + 2*(l-i) + 3;
      int hstep = d + 1;
      hA += hstep; hB += hstep; hM += hstep; hMp += hstep;
      d += 2;
    }
    if (j == 0) {
#pragma unroll
      for (int cs = 0; cs < 2; ++cs) { P[cs] *= 0.5f; Q2[cs] *= 0.5f; }
    }
#pragma unroll
    for (int cs = 0; cs < 2; ++cs) {
      PF[cs*LH2 + t] = P[cs]; Q1F[cs*LH2 + t] = Q1[cs];
      Q2F[cs*LH2 + t] = Q2[cs]; Q3F[cs*LH2 + t] = Q3[cs];
    }
  }
  __syncthreads();
  double beta = ((double)ib + 0.5) * (PI_D / (double)NG);
  float qwv = (float)(sin(beta) * PI_D / (2.0*(double)NG*(double)NG*(double)NG));
  for (int cs = 0; cs < 2; ++cs) {
    for (int t = tid; t < LH*NGB; t += BS) {
      int i = t / NGB, ig0 = (t % NGB)*IGB;
      f4 rc = 0.f, rs = 0.f;
      const float* Pr  = PF  + cs*LH2 + i*LH;
      const float* Q1r = Q1F + cs*LH2 + i*LH;
      const float* Q2r = Q2F + cs*LH2 + i*LH;
      const float* Q3r = Q3F + cs*LH2 + i*LH;
      for (int k = 0; k <= L; ++k) {
        float p = Pr[k], q1 = Q1r[k], q2 = Q2r[k], q3 = Q3r[k];
        f4 c = *(const f4*)(tck + k*NG + ig0);
        f4 s = *(const f4*)(tsk + k*NG + ig0);
        rc += c*p + s*q1;
        rs += c*q2 + s*q3;
      }
      *(f4*)(Rc + i*NG + ig0) = rc;
      *(f4*)(Rs + i*NG + ig0) = rs;
    }
    __syncthreads();
    size_t obase = (((size_t)b0*F + (f0+cs))*NG + ib)*(size_t)(NG*NG);
    for (int t = tid; t < NG*NGB; t += BS) {
      int ia = t / NGB, ig0 = (t % NGB)*IGB;
      f4 acc = 0.f;
      for (int k = 0; k <= L; ++k) {
        float ca = tck[k*NG + ia], sa = tsk[k*NG + ia];
        f4 rc = *(const f4*)(Rc + k*NG + ig0);
        f4 rs = *(const f4*)(Rs + k*NG + ig0);
        acc += ca*rc - sa*rs;
      }
      f4 res;
#pragma unroll
      for (int jj = 0; jj < 4; ++jj) res[jj] = fmaxf(acc[jj], 0.0f) * qwv;
      *(f4*)(fw + obase + ia*NG + ig0) = res;
    }
    __syncthreads();
  }
}

// both psi GEMMs + act1 synthesis in ONE launch (independent work, time-shared chip)
// shbuf layout (floats, 16B-aligned segments): PF 0..884, Q1F 884, Q2F 1768, Q3F 2652,
// uni 3536 (1324), tck 4860 (420), tsk 5280 (420) -> 5700 total = 22.8 KB
__global__ __launch_bounds__(256) void k_gs(const float* __restrict__ A1, const float* __restrict__ B1,
                                            const unsigned* __restrict__ lut1, float* __restrict__ C1,
                                            int M1, int N1, int NP1, int FO1,
                                            const float* __restrict__ A2, const float* __restrict__ B2,
                                            const unsigned* __restrict__ lut2, float* __restrict__ C2,
                                            int M2, int N2, int NP2, int FO2,
                                            int K, int nbx1, int nb1, int nbx2, int nb12, float alpha,
                                            const float* __restrict__ psi1, const float* __restrict__ coeff,
                                            const float* __restrict__ dr20g1,
                                            const float* __restrict__ t1ck, const float* __restrict__ t1sk,
                                            float* __restrict__ fwbuf) {
  __shared__ __align__(16) float shbuf[5700];
  int bid = blockIdx.x, tid = threadIdx.x;
  if (bid < nb1) {
    int tm = (bid % nbx1)*64, tn = (bid / nbx1)*64;
    gemm_body(A1, B1, lut1, C1, M1, N1, NP1, K, FO1, tm, tn, alpha,
              (float(*)[16][68])shbuf, (float(*)[16][68])(shbuf + 2176), tid);
  } else if (bid < nb12) {
    int b2 = bid - nb1;
    int tm = (b2 % nbx2)*64, tn = (b2 / nbx2)*64;
    gemm_body(A2, B2, lut2, C2, M2, N2, NP2, K, FO2, tm, tn, alpha,
              (float(*)[16][68])shbuf, (float(*)[16][68])(shbuf + 2176), tid);
  } else {
    int b2 = bid - nb12;
    int ib = b2 % 20;
    int r = b2 / 20;
    int f0 = (r % 32)*2;
    int b0 = r / 32;
    syn1b_body(psi1, coeff, dr20g1, t1ck, t1sk, fwbuf, ib, f0, b0, tid,
               shbuf, shbuf + 884, shbuf + 1768, shbuf + 2652,
               shbuf + 3536, shbuf + 4860, shbuf + 5280);
  }
}

// fused ana-reduce + pack: hA[8*FI*loff(l) + (b*d+m)*(FI*d) + i*d+u] = sum_c part[c][bi][s]
__global__ __launch_bounds__(256) void k_anapack(const float* __restrict__ part, const unsigned* __restrict__ lut,
                                                 float* __restrict__ hA, int FI, int S, int nch) {
  int e = blockIdx.x*256 + threadIdx.x;
  int total = 8*FI*S;
  if (e >= total) return;
  int bi = e / S, s = e - bi*S;
  float a = 0.f;
  for (int c = 0; c < nch; ++c) a += part[(size_t)c*total + e];
  unsigned u3 = lut[s];
  int l = u3 & 255, u = (u3>>8)&255, m = (u3>>16)&255;
  int d = 2*l+1;
  int b = bi / FI, i = bi - b*FI;
  hA[(size_t)8*FI*loff(l) + (size_t)(b*d+m)*(FI*d) + i*d + u] = a;
}

// split-K packed per-l block linear, ping-pong LDS + f4 staging. Writes scaled partials.
__global__ __launch_bounds__(256) void k_linsk(const float* __restrict__ hA, const float* __restrict__ psiP,
                                               float* __restrict__ part, int FI, int FO, int S,
                                               int maxNT, int KC) {
  int l = blockIdx.z;
  int d = 2*l+1, off = loff(l);
  int Ml = 8*d, Nl = FO*d, Kl = FI*d;
  int tm = blockIdx.x*64;
  int tn = ((int)blockIdx.y % maxNT)*64;
  int kci = (int)blockIdx.y / maxNT;
  int k0s = kci*KC;
  if (tm >= Ml || tn >= Nl || k0s >= Kl) return;
  int k1s = min(Kl, k0s + KC);
  float alpha = 1.0f/sqrtf((float)(FI*d));
  const float* Ab = hA + (size_t)8*FI*off;
  const float* Bb = psiP + (size_t)FI*FO*off;
  __shared__ __align__(16) float As[2][16][68], Bs[2][16][68];
  int tid = threadIdx.x, ty = tid/16, tx = tid%16;
  int arr = tid>>2, akq = (tid&3)*4;
  int bkk = tid>>4, bcq = (tid&15)*4;
  bool aok = (tm + arr) < Ml;
  const float* Arow = Ab + (size_t)(tm + arr)*Kl;
  const f4 FZ = 0.f;
  float acc[4][4] = {};
  f4 ra, rb;
#define LOADL(k0)                                                        \
  {                                                                      \
    ra = aok ? *(const f4*)&Arow[(k0) + akq] : FZ;                       \
    rb = *(const f4*)&Bb[(size_t)((k0) + bkk)*Nl + tn + bcq];            \
  }
#define STOREL(b)                                                        \
  {                                                                      \
    _Pragma("unroll")                                                    \
    for (int jj = 0; jj < 4; ++jj) As[b][akq+jj][arr] = ra[jj];          \
    *(f4*)&Bs[b][bkk][bcq] = rb;                                         \
  }
  LOADL(k0s);
  STOREL(0);
  __syncthreads();
  int cur = 0;
  for (int k0 = k0s; k0 < k1s; k0 += 16) {
    bool nxt = (k0 + 16) < k1s;
    if (nxt) { LOADL(k0 + 16); }
#pragma unroll
    for (int kk = 0; kk < 16; ++kk) {
      f4 av = *(const f4*)&As[cur][kk][ty*4];
      f4 bv = *(const f4*)&Bs[cur][kk][tx*4];
#pragma unroll
      for (int q = 0; q < 4; ++q)
#pragma unroll
        for (int r2 = 0; r2 < 4; ++r2) acc[q][r2] += av[q]*bv[r2];
    }
    if (nxt) { STOREL(cur ^ 1); __syncthreads(); cur ^= 1; }
  }
#undef LOADL
#undef STOREL
  size_t pbase = (size_t)kci * (size_t)8*FO*S;
  for (int q = 0; q < 4; ++q) {
    int r = tm + ty*4 + q; if (r >= Ml) continue;
    int b = r / d, m = r - b*d;
    for (int r2 = 0; r2 < 4; ++r2) {
      int c = tn + tx*4 + r2; if (c >= Nl) continue;
      int o = c / d, v = c - o*d;
      part[pbase + (size_t)(b*FO + o)*S + off + v*d + m] = alpha*acc[q][r2];
    }
  }
}

// non-rank1 synthesis, u-PAIR-FOLDED stage A, with INLINE split-K partial sum on load.
template<int L, int NG, int F, int BS>
__global__ __launch_bounds__(BS) void k_syn(const float* __restrict__ part, int thr1, int thr2, int total,
                                            const float* __restrict__ drg,
                                            const float* __restrict__ gtck, const float* __restrict__ gtsk,
                                            float* __restrict__ fw) {
  constexpr int LH = L+1;
  constexpr int LH2 = LH*LH;
  constexpr int S = (L+1)*(2*L+1)*(2*L+3)/3;
  constexpr int RCSZ = LH*NG;
  constexpr int UNI = (S > 2*RCSZ) ? S : 2*RCSZ;
  constexpr int IGB = (NG % 4 == 0) ? 4 : 2;
  constexpr int NGB = NG / IGB;
  using VecT = typename VW<IGB>::T;
  __shared__ float PF[LH2], Q1F[LH2], Q2F[LH2], Q3F[LH2];
  __shared__ __align__(16) float uni[UNI];
  __shared__ __align__(16) float tck[LH*NG], tsk[LH*NG];
  float* hrow = uni;
  float* Rc = uni;
  float* Rs = uni + RCSZ;
  int ib = blockIdx.x, f = blockIdx.y, b = blockIdx.z;
  int tid = threadIdx.x;
  for (int t = tid; t < S; t += BS) {
    size_t e = ((size_t)b*F + f)*S + t;
    float a = part[e];
    if (t >= thr1) a += part[(size_t)total + e];
    if (t >= thr2) a += part[2*(size_t)total + e];
    hrow[t] = a;
  }
  for (int t = tid; t < LH*NG; t += BS) { tck[t] = gtck[t]; tsk[t] = gtsk[t]; }
  __syncthreads();
  const float* drb = drg + (size_t)ib*S;
  for (int t = tid; t < LH2; t += BS) {
    int i = t / LH, j = t % LH;
    int lmin = max(i, j);
    float P = 0.f, Q1 = 0.f, Q2 = 0.f, Q3 = 0.f;
    int d = 2*lmin+1;
    int j2 = 2*j;
    int drip = loff(lmin) + (lmin+i)*d + (lmin-j);
    int drim = loff(lmin) + (lmin-i)*d + (lmin-j);
    for (int l = lmin; l <= L; ++l) {
      float ap_ = drb[drip], app = drb[drip + j2];
      float am_ = 0.f, amp = 0.f;
      if (i > 0) { am_ = drb[drim]; amp = drb[drim + j2]; }
      float hp1 = hrow[drip], hp2 = hrow[drip + j2];
      float hm1 = hrow[drim], hm2 = hrow[drim + j2];
      P  += ap_*hp1 + app*hp2 + am_*hm1 + amp*hm2;
      Q1 += app*hp1 - ap_*hp2 + amp*hm1 - am_*hm2;
      Q2 += ap_*hm1 + app*hm2 - am_*hp1 - amp*hp2;
      Q3 += app*hm1 - ap_*hm2 - amp*hp1 + am_*hp2;
      drip += d*d + d + 2*(l+i) + 3;
      drim += d*d + d + 2*(l-i) + 3;
      d += 2;
    }
    if (j == 0) { P *= 0.5f; Q2 *= 0.5f; }
    PF[t] = P; Q1F[t] = Q1; Q2F[t] = Q2; Q3F[t] = Q3;
  }
  __syncthreads();
  for (int t = tid; t < LH*NGB; t += BS) {
    int i = t / NGB, ig0 = (t % NGB)*IGB;
    VecT rc = 0.f, rs = 0.f;
    const float* Pr  = PF  + i*LH;
    const float* Q1r = Q1F + i*LH;
    const float* Q2r = Q2F + i*LH;
    const float* Q3r = Q3F + i*LH;
    for (int k = 0; k <= L; ++k) {
      float p = Pr[k], q1 = Q1r[k], q2 = Q2r[k], q3 = Q3r[k];
      VecT c = *(const VecT*)(tck + k*NG + ig0);
      VecT s = *(const VecT*)(tsk + k*NG + ig0);
      rc += c*p + s*q1;
      rs += c*q2 + s*q3;
    }
    *(VecT*)(Rc + i*NG + ig0) = rc;
    *(VecT*)(Rs + i*NG + ig0) = rs;
  }
  __syncthreads();
  double beta = ((double)ib + 0.5) * (PI_D / (double)NG);
  float qwv = (float)(sin(beta) * PI_D / (2.0*(double)NG*(double)NG*(double)NG));
  size_t obase = (((size_t)b*F + f)*NG + ib)*(size_t)(NG*NG);
  for (int t = tid; t < NG*NGB; t += BS) {
    int ia = t / NGB, ig0 = (t % NGB)*IGB;
    VecT acc = 0.f;
    for (int k = 0; k <= L; ++k) {
      float ca = tck[k*NG + ia], sa = tsk[k*NG + ia];
      VecT rc = *(const VecT*)(Rc + k*NG + ig0);
      VecT rs = *(const VecT*)(Rs + k*NG + ig0);
      acc += ca*rc - sa*rs;
    }
    VecT res;
#pragma unroll
    for (int jj = 0; jj < IGB; ++jj) res[jj] = fmaxf(acc[jj], 0.0f) * qwv;
    *(VecT*)(fw + obase + ia*NG + ig0) = res;
  }
}

// factorized SO(3) grid analysis to lmax LO, ib-chunked, PARITY-FOLDED on all
// four DFT axes (output mu_u/mu_m and inner ia/ig). hpart[ibc][b][f][SO]
template<int LO, int NG, int F, int IBN, int BS>
__global__ __launch_bounds__(BS) void k_ana(const float* __restrict__ fw, const float* __restrict__ drg,
                                            const float* __restrict__ gtck, const float* __restrict__ gtsk,
                                            float* __restrict__ hpart) {
  constexpr int LH = LO+1;
  constexpr int LHP = (LH+3)&~3;
  constexpr int NH = NG/2;               // NG even (20,10,6)
  constexpr int SO = (LO+1)*(2*LO+1)*(2*LO+3)/3;
  constexpr int ME = (SO+BS-1)/BS;
  __shared__ float fws[NG*NG];
  __shared__ float fe[(NH+1)*NG], fo[(NH-1)*NG];
  __shared__ float drs[SO];
  __shared__ float FcF[LH*NG], FsF[LH*NG];
  __shared__ float FcFe[LH*(NH+1)], FcFo[LH*(NH-1)];
  __shared__ float FsFe[LH*(NH+1)], FsFo[LH*(NH-1)];
  __shared__ float Gcc[LH*LHP], Gcs[LH*LHP], Gsc[LH*LHP], Gss[LH*LHP];
  __shared__ float tc[LH*NG], ts[LH*NG];  // k-major, rows 0..LO
  __shared__ unsigned lut[SO];
  int f = blockIdx.x, b = blockIdx.y, ibc = blockIdx.z, tid = threadIdx.x;
  for (int t = tid; t < LH*NG; t += BS) { tc[t] = gtck[t]; ts[t] = gtsk[t]; }
  for (int t = tid; t < SO; t += BS) {
    int l = 0; while (l < LO && t >= loff(l+1)) ++l;
    int j = t - loff(l), d = 2*l+1;
    int iu = j/d, im = j - iu*d;
    lut[t] = (unsigned)l | ((unsigned)iu<<8) | ((unsigned)im<<16);
  }
  float rf[ME];
#pragma unroll
  for (int e = 0; e < ME; ++e) rf[e] = 0.f;
  __syncthreads();
  int ib0 = ibc*IBN, ib1 = min(NG, ib0 + IBN);
  for (int ib = ib0; ib < ib1; ++ib) {
    size_t base = (((size_t)b*F + f)*NG + ib)*(size_t)(NG*NG);
    for (int t = tid; t < NG*NG; t += BS) fws[t] = fw[base + t];
    for (int t = tid; t < SO; t += BS) drs[t] = drg[(size_t)ib*SO + t];
    __syncthreads();
    // fold fw over ia (cos even / sin odd around ia -> NG-ia)
    for (int t = tid; t < (NH+1)*NG; t += BS) {
      int ia = t / NG, ig = t % NG;
      float v = fws[ia*NG + ig];
      if (ia > 0 && ia < NH) v += fws[(NG-ia)*NG + ig];
      fe[t] = v;
    }
    for (int t = tid; t < (NH-1)*NG; t += BS) {
      int ia = t / NG + 1, ig = t % NG;
      fo[t] = fws[ia*NG + ig] - fws[(NG-ia)*NG + ig];
    }
    __syncthreads();
    // stage 1 (folded): FcF[k][ig], FsF[k][ig] for k = |mu_u| = 0..LO
    for (int t = tid; t < LH*NG; t += BS) {
      int k = t / NG, ig = t % NG;
      float fc = 0.f, fs = 0.f;
      for (int ia = 0; ia <= NH; ++ia) fc += tc[k*NG + ia]*fe[ia*NG + ig];
      for (int ia = 1; ia < NH;  ++ia) fs += ts[k*NG + ia]*fo[(ia-1)*NG + ig];
      FcF[t] = fc; FsF[t] = fs;
    }
    __syncthreads();
    // fold F over ig
    for (int t = tid; t < LH*(NH+1); t += BS) {
      int k = t / (NH+1), jg = t % (NH+1);
      float c = FcF[k*NG + jg], s = FsF[k*NG + jg];
      if (jg > 0 && jg < NH) { c += FcF[k*NG + NG - jg]; s += FsF[k*NG + NG - jg]; }
      FcFe[t] = c; FsFe[t] = s;
    }
    for (int t = tid; t < LH*(NH-1); t += BS) {
      int k = t / (NH-1), jg = t % (NH-1) + 1;
      FcFo[t] = FcF[k*NG + jg] - FcF[k*NG + NG - jg];
      FsFo[t] = FsF[k*NG + jg] - FsF[k*NG + NG - jg];
    }
    __syncthreads();
    // stage 2 (folded): G**[k][km] for km = |mu_m| = 0..LO
    for (int t = tid; t < LH*LH; t += BS) {
      int k = t / LH, km = t % LH;
      float gcc = 0.f, gcs = 0.f, gsc = 0.f, gss = 0.f;
      for (int jg = 0; jg <= NH; ++jg) {
        float tcv = tc[km*NG + jg];
        gcc += tcv*FcFe[k*(NH+1) + jg];
        gsc += tcv*FsFe[k*(NH+1) + jg];
      }
      for (int jg = 1; jg < NH; ++jg) {
        float tsv = ts[km*NG + jg];
        gcs += tsv*FcFo[k*(NH-1) + jg - 1];
        gss += tsv*FsFo[k*(NH-1) + jg - 1];
      }
      Gcc[k*LHP + km] = gcc; Gcs[k*LHP + km] = gcs;
      Gsc[k*LHP + km] = gsc; Gss[k*LHP + km] = gss;
    }
    __syncthreads();
    // stage 3: per-element accumulate with sign reconstruction
#pragma unroll
    for (int e = 0; e < ME; ++e) {
      int t = tid + e*BS;
      if (t < SO) {
        unsigned u3 = lut[t];
        int l = u3 & 255, iu = (u3>>8)&255, im = (u3>>16)&255;
        int d = 2*l+1;
        int bidx = loff(l) + iu*d + im;
        int ru = (d-1-2*iu)*d, rm = d-1-2*im;
        int du_ = iu - l, dm_ = im - l;
        int ku = (du_ < 0) ? -du_ : du_;
        int km = (dm_ < 0) ? -dm_ : dm_;
        int gi = ku*LHP + km;
        float d1 = drs[bidx], d2 = drs[bidx+rm], d3 = drs[bidx+ru], d4 = drs[bidx+ru+rm];
        float g1 = Gcc[gi], g2 = Gcs[gi], g3 = Gsc[gi], g4 = Gss[gi];
        if (dm_ < 0) { g2 = -g2; g4 = -g4; }
        if (du_ < 0) { g3 = -g3; g4 = -g4; }
        rf[e] += g1*d1 - g2*d2 + g3*d3 - g4*d4;
      }
    }
    __syncthreads();
  }
  size_t obase = (size_t)ibc*((size_t)8*F*SO) + ((size_t)b*F + f)*SO;
#pragma unroll
  for (int e = 0; e < ME; ++e) {
    int t = tid + e*BS;
    if (t < SO) hpart[obase + t] = rf[e];
  }
}

// final two FC layers. one block, 1024 threads.
__global__ __launch_bounds__(1024) void k_fc(const float* __restrict__ h4, const float* __restrict__ w1,
                                             const float* __restrict__ b1, const float* __restrict__ w2,
                                             const float* __restrict__ b2, float* __restrict__ out) {
  __shared__ float t1[1024];
  int tid = threadIdx.x;
  {
    int b = tid >> 7, j = tid & 127;
    float a = b1[j];
    const float* hr = h4 + b*256;
    for (int k = 0; k < 256; ++k) a += hr[k]*w1[k*128 + j];
    t1[tid] = fmaxf(a, 0.f);
  }
  __syncthreads();
  if (tid < 80) {
    int b = tid / 10, j = tid % 10;
    float a = b2[j];
    for (int k = 0; k < 128; ++k) a += t1[b*128 + k]*w2[k*10 + j];
    out[b*10 + j] = a;
  }
}

extern "C" void kernel_launch(void* const* d_in, const int* in_sizes, int n_in,
                              void* d_out, int out_size, void* d_ws, size_t ws_size,
                              hipStream_t stream) {
  const float* x    = (const float*)d_in[0];
  const float* w1   = (const float*)d_in[1];
  const float* w2   = (const float*)d_in[2];
  const float* w3   = (const float*)d_in[3];
  const float* fcw1 = (const float*)d_in[4];
  const float* fcb1 = (const float*)d_in[5];
  const float* fcw2 = (const float*)d_in[6];
  const float* fcb2 = (const float*)d_in[7];
  float* out = (float*)d_out;

  float* base = (float*)d_ws;
  size_t off = 0;
  auto alloc = [&](size_t n) -> float* { float* p = base + off; off += (n + 63) & ~(size_t)63; return p; };

  float* drc60  = alloc((size_t)60*441);
  float* drc24  = alloc((size_t)24*441);
  float* psi1   = alloc((size_t)64*441);
  float* coeff  = alloc((size_t)8*441);
  float* drK2   = alloc((size_t)168*S_L10);
  float* drK3   = alloc((size_t)168*S_L5);
  float* dk2    = alloc((size_t)168*1772 + 64);   // padded stride 1772
  float* dk3    = alloc((size_t)168*288 + 64);    // padded stride 288
  float* psi2P  = alloc((size_t)8192*S_L10);
  float* psi3P  = alloc((size_t)32768*S_L5);
  float* dr20g1 = alloc((size_t)20*S_L20);
  float* dr10g1 = alloc((size_t)20*S_L10);
  float* dr10g2 = alloc((size_t)10*S_L10);
  float* dr5g2  = alloc((size_t)10*S_L5);
  float* dr5g3  = alloc((size_t)6*S_L5);
  float* dr0g3  = alloc(6);
  float* t1ck   = alloc((size_t)21*20);
  float* t1sk   = alloc((size_t)21*20);
  float* t2ck   = alloc((size_t)11*10);
  float* t2sk   = alloc((size_t)11*10);
  float* t3ck   = alloc((size_t)6*6);
  float* t3sk   = alloc((size_t)6*6);
  float* lut10  = alloc((size_t)S_L10);   // unsigned, same size as float
  float* lut5   = alloc((size_t)S_L5);
  float* fwbuf  = alloc((size_t)8*64*8000);         // aliased: fw1b / fw2b / fw3b
  float* scr    = alloc((size_t)3*8*128*S_L10);     // aliased: hp1 / part2 / hp2 / part3
  float* hA2    = alloc((size_t)8*64*S_L10);
  float* hA3    = alloc((size_t)8*128*S_L5);
  float* h4     = alloc((size_t)8*256);
  if (off * sizeof(float) > ws_size) return;

  const float inv_s168 = 0.07715167498104595f;  // 1/sqrt(168)
  const int KC = 512;

  // ---- ALL constant tables, two launches ----
  k_tables<<<dim3(942), 256, 0, stream>>>(dr20g1, drK2, dr10g1, dr10g2, drK3, dr5g2, dr5g3, dr0g3,
                                          drc60, drc24, t1ck, t1sk, t2ck, t2sk, t3ck, t3sk,
                                          (unsigned*)lut10, (unsigned*)lut5);
  k_tab2<<<dim3(1904), 256, 0, stream>>>(drc24, w1, psi1, drK2, dk2, drK3, dk3, drc60, x, coeff);
  // ---- both psi GEMMs + act1 synthesis (2-combo, 22.8 KB LDS) in one launch ----
  k_gs<<<dim3(3584 + 2560 + 5120), 256, 0, stream>>>(
      w2, dk2, (const unsigned*)lut10, psi2P, 8192,  S_L10, 1772, 128,
      w3, dk3, (const unsigned*)lut5,  psi3P, 32768, S_L5,  288,  256,
      168, 128, 3584, 512, 6144, inv_s168,
      psi1, coeff, dr20g1, t1ck, t1sk, fwbuf);

  // ---- act1 analysis ----
  k_ana<10,20,64,4,256><<<dim3(64,8,5),  256, 0, stream>>>(fwbuf, dr10g1, t1ck, t1sk, scr);
  // ---- fused ana-reduce + pack, then so3 linear 2 (partials summed inside syn2) ----
  k_anapack<<<dim3((8*64*S_L10+255)/256), 256, 0, stream>>>(scr, (const unsigned*)lut10, hA2, 64, S_L10, 5);
  k_linsk<<<dim3(3, 42*3, 11), 256, 0, stream>>>(hA2, psi2P, scr, 64, 128, S_L10, 42, KC);
  // ---- act2 (syn sums lin2 split-K partials inline: thr = loff(4)=84, loff(8)=680) ----
  k_syn<10,10,128,128><<<dim3(10,128,8), 128, 0, stream>>>(scr, 84, 680, 8*128*S_L10, dr10g2, t2ck, t2sk, fwbuf);
  k_ana<5,10,128,5,128><<<dim3(128,8,2),  128, 0, stream>>>(fwbuf, dr5g2, t2ck, t2sk, scr);
  // ---- fused ana-reduce + pack, then so3 linear 3 (partials summed inside syn3) ----
  k_anapack<<<dim3((8*128*S_L5+255)/256), 256, 0, stream>>>(scr, (const unsigned*)lut5, hA3, 128, S_L5, 2);
  k_linsk<<<dim3(2, 44*3, 6), 256, 0, stream>>>(hA3, psi3P, scr, 128, 256, S_L5, 44, KC);
  // ---- act3 (syn sums lin3 split-K partials inline: thr = loff(2)=10, loff(4)=84) ----
  k_syn<5,6,256,64><<<dim3(6,256,8), 64, 0, stream>>>(scr, 10, 84, 8*256*S_L5, dr5g3, t3ck, t3sk, fwbuf);
  k_ana<0,6,256,6,64><<<dim3(256,8,1), 64, 0, stream>>>(fwbuf, dr0g3, t3ck, t3sk, h4);
  // ---- FC head ----
  k_fc<<<dim3(1), 1024, 0, stream>>>(h4, fcw1, fcb1, fcw2, fcb2, out);
}

// Round 20
// 612.344 us; speedup vs baseline: 1.0391x; 1.0391x over previous
//
#include <hip/hip_runtime.h>

#define PI_D 3.14159265358979323846

constexpr int S_L20 = 12341;  // sum_{l<=20} (2l+1)^2
constexpr int S_L10 = 1771;
constexpr int S_L5  = 286;
constexpr int C_L20 = 441;    // (20+1)^2

typedef float f4 __attribute__((ext_vector_type(4)));
typedef float f2 __attribute__((ext_vector_type(2)));
template<int W> struct VW;
template<> struct VW<4> { using T = f4; };
template<> struct VW<2> { using T = f2; };

__host__ __device__ __forceinline__ int loff(int l) { return l*(4*l*l-1)/3; }

__device__ __forceinline__ int isqrt_dev(int c) {
  int l = (int)sqrtf((float)c);
  while ((l+1)*(l+1) <= c) ++l;
  while (l*l > c) --l;
  return l;
}

// small Wigner-d d^l_{mp,m}(beta); cpw/spw are power tables of cos(beta/2), sin(beta/2)
__device__ double d_small(int l, int mp, int m, const double* cpw, const double* spw, const double* fact) {
  double pref = sqrt(fact[l+mp]*fact[l-mp]*fact[l+m]*fact[l-m]);
  int k0 = max(0, m-mp), k1 = min(l+m, l-mp);
  double val = 0.0;
  for (int k = k0; k <= k1; ++k) {
    double den = fact[l+m-k]*fact[k]*fact[mp-m+k]*fact[l-mp-k];
    double t = (pref/den)*cpw[2*l+m-mp-2*k]*spw[mp-m+2*k];
    val += ((mp-m+k)&1) ? -t : t;
  }
  return val;
}

// real-basis Wigner-d element, row ap, col bp (signed, in [-l,l]).
__device__ double dr_elem(int l, int ap, int bp, const double* cpw, const double* spw, const double* fact) {
  const double IR2 = 0.70710678118654752440;
  if (ap == 0 && bp == 0) return d_small(l,0,0,cpw,spw,fact);
  if (bp == 0) {
    if (ap < 0) return 0.0;
    double sp = (ap&1)? -1.0: 1.0;
    return IR2*(d_small(l,-ap,0,cpw,spw,fact) + sp*d_small(l,ap,0,cpw,spw,fact));
  }
  if (ap == 0) {
    if (bp < 0) return 0.0;
    double sm = (bp&1)? -1.0: 1.0;
    return IR2*(d_small(l,0,-bp,cpw,spw,fact) + sm*d_small(l,0,bp,cpw,spw,fact));
  }
  if (ap > 0 && bp > 0) {
    double sp = (ap&1)?-1.0:1.0, sm = (bp&1)?-1.0:1.0;
    return 0.5*(d_small(l,-ap,-bp,cpw,spw,fact) + sm*d_small(l,-ap,bp,cpw,spw,fact)
              + sp*d_small(l,ap,-bp,cpw,spw,fact) + sp*sm*d_small(l,ap,bp,cpw,spw,fact));
  }
  if (ap < 0 && bp < 0) {
    int mp = -ap, m = -bp;
    double sp = (mp&1)?-1.0:1.0, sm = (m&1)?-1.0:1.0;
    return 0.5*(d_small(l,-mp,-m,cpw,spw,fact) - sm*d_small(l,-mp,m,cpw,spw,fact)
              - sp*d_small(l,mp,-m,cpw,spw,fact) + sp*sm*d_small(l,mp,m,cpw,spw,fact));
  }
  return 0.0;
}

// beta of point p: mode 0: (p+0.5)*pi/gridn ; mode 1: so3 near-identity ; mode 2: s2 near-identity
__device__ double beta_of(int mode, int p, int gridn) {
  if (mode == 0) return (p + 0.5) * (PI_D / gridn);
  if (mode == 1) return (double)(((p >> 3) % 3) + 1) * (PI_D / 24.0);
  return (double)((p % 3) + 1) * (PI_D / 24.0);
}

// ALL small constant tables in ONE launch: dr tables + drc tables + trig + luts.
__global__ __launch_bounds__(256) void k_tables(float* dr20g1, float* drK2, float* dr10g1, float* dr10g2,
                                                float* drK3, float* dr5g2, float* dr5g3, float* dr0g3,
                                                float* drc60, float* drc24,
                                                float* t1c, float* t1s, float* t2c, float* t2s,
                                                float* t3c, float* t3s,
                                                unsigned* lut10, unsigned* lut5) {
  __shared__ double cpw[44], spw[44], fact[44];
  int b = blockIdx.x;
  int tid = threadIdx.x;
  if (b < 846) {
    // ---- full real Wigner-d tables ----
    float* out; int lmax, S, mode, gridn, p, chunk;
    if (b < 260)      { out=dr20g1; lmax=20; S=S_L20; mode=0; gridn=20; p=b/13;        chunk=b%13; }
    else if (b < 596) { int i=b-260; out=drK2;   lmax=10; S=S_L10; mode=1; gridn=0;  p=i/2; chunk=i%2; }
    else if (b < 636) { int i=b-596; out=dr10g1; lmax=10; S=S_L10; mode=0; gridn=20; p=i/2; chunk=i%2; }
    else if (b < 656) { int i=b-636; out=dr10g2; lmax=10; S=S_L10; mode=0; gridn=10; p=i/2; chunk=i%2; }
    else if (b < 824) { int i=b-656; out=drK3;   lmax=5;  S=S_L5;  mode=1; gridn=0;  p=i;   chunk=0; }
    else if (b < 834) { int i=b-824; out=dr5g2;  lmax=5;  S=S_L5;  mode=0; gridn=10; p=i;   chunk=0; }
    else if (b < 840) { int i=b-834; out=dr5g3;  lmax=5;  S=S_L5;  mode=0; gridn=6;  p=i;   chunk=0; }
    else              { int i=b-840; out=dr0g3;  lmax=0;  S=1;     mode=0; gridn=6;  p=i;   chunk=0; }
    double beta_ = beta_of(mode, p, gridn);
    if (tid == 0) {
      double cb_ = cos(beta_*0.5), sb_ = sin(beta_*0.5);
      cpw[0]=1.0; spw[0]=1.0; fact[0]=1.0;
      for (int i_=1;i_<44;++i_){cpw[i_]=cpw[i_-1]*cb_; spw[i_]=spw[i_-1]*sb_; fact[i_]=fact[i_-1]*(double)i_;}
    }
    __syncthreads();
    int base = chunk*1024;
    int end = min(S, base + 1024);
    for (int t = base + tid; t < end; t += 256) {
      int l = 0; while (l < lmax && t >= loff(l+1)) ++l;
      int j = t - loff(l), d = 2*l+1;
      int a = j/d, bb = j%d;
      double v = dr_elem(l, a-l, bb-l, cpw, spw, fact) * sqrt(2.0*l+1.0);
      out[(size_t)p*S + t] = (float)v;
    }
  } else if (b < 930) {
    // ---- m=0 column tables ----
    int bb = b - 846;
    float* out; int mode, gridn, p;
    if (bb < 60) { out = drc60; mode = 0; gridn = 60; p = bb; }
    else         { out = drc24; mode = 2; gridn = 0;  p = bb - 60; }
    double beta_ = beta_of(mode, p, gridn);
    if (tid == 0) {
      double cb_ = cos(beta_*0.5), sb_ = sin(beta_*0.5);
      cpw[0]=1.0; spw[0]=1.0; fact[0]=1.0;
      for (int i_=1;i_<44;++i_){cpw[i_]=cpw[i_-1]*cb_; spw[i_]=spw[i_-1]*sb_; fact[i_]=fact[i_-1]*(double)i_;}
    }
    __syncthreads();
    for (int t = tid; t < C_L20; t += 256) {
      int l = isqrt_dev(t);
      int u = t - l*l - l;
      double v;
      if (u < 0) v = 0.0;
      else if (u == 0) v = d_small(l,0,0,cpw,spw,fact);
      else {
        double sp = (u&1)? -1.0: 1.0;
        v = 0.70710678118654752440*(d_small(l,-u,0,cpw,spw,fact) + sp*d_small(l,u,0,cpw,spw,fact));
      }
      out[(size_t)p*C_L20 + t] = (float)(v * sqrt(2.0*l+1.0));
    }
  } else if (b < 933) {
    // ---- trig tables ----
    int t = (b - 930)*256 + tid;
    if (t < 420) {
      int k = t/20, ig = t%20;
      double ang = (double)k*(double)ig*(2.0*PI_D/20.0);
      t1c[t] = (float)cos(ang); t1s[t] = (float)sin(ang);
    } else if (t < 530) {
      int i = t-420, k = i/10, ig = i%10;
      double ang = (double)k*(double)ig*(2.0*PI_D/10.0);
      t2c[i] = (float)cos(ang); t2s[i] = (float)sin(ang);
    } else if (t < 566) {
      int i = t-530, k = i/6, ig = i%6;
      double ang = (double)k*(double)ig*(2.0*PI_D/6.0);
      t3c[i] = (float)cos(ang); t3s[i] = (float)sin(ang);
    }
  } else {
    // ---- s->(l,u,v) LUTs ----
    int t = (b - 933)*256 + tid;
    unsigned* lut; int s, lmax;
    if (t < S_L10) { lut = lut10; s = t; lmax = 10; }
    else if (t < S_L10 + S_L5) { lut = lut5; s = t - S_L10; lmax = 5; }
    else return;
    int l = 0; while (l < lmax && s >= loff(l+1)) ++l;
    int j = s - loff(l), d = 2*l+1;
    int u = j/d, v = j - u*d;
    lut[s] = (unsigned)l | ((unsigned)u<<8) | ((unsigned)v<<16);
  }
}

// psi1 + both D_K tables + coeff (FS2 computed on the fly) in ONE launch.
__global__ __launch_bounds__(256) void k_tab2(const float* __restrict__ drc24, const float* __restrict__ w1,
                                              float* __restrict__ psi1,
                                              const float* __restrict__ drk2, float* __restrict__ DK2,
                                              const float* __restrict__ drk3, float* __restrict__ DK3,
                                              const float* __restrict__ drc60, const float* __restrict__ x,
                                              float* __restrict__ coeff) {
  __shared__ float red[2048];
  __shared__ float cu[60], su[60], sbq[60];
  int b = blockIdx.x, tid = threadIdx.x;
  if (b < 111) {
    // ---- psi1 ----
    int e = b*256 + tid;
    if (e >= 64*441) return;
    int o = e / 441, c = e % 441;
    int l = isqrt_dev(c);
    int u = c - l*l - l;
    float acc = 0.f;
    for (int p = 0; p < 24; ++p) {
      double alpha = (double)(p/3)*(PI_D/4.0);
      double y = cos((double)u*alpha)*(double)drc24[p*441+c] + sin((double)u*alpha)*(double)drc24[p*441 + (c-2*u)];
      acc += (float)y * w1[o*24 + p];
    }
    psi1[e] = acc * 0.20412414523193150818f;
  } else if (b < 1463) {
    // ---- both D_K tables (padded strides) ----
    int e0 = (b - 111)*256 + tid;
    const float* drk; float* DK; int S, NP, lmax, e;
    if (e0 < 168*1772) { drk = drk2; DK = DK2; S = S_L10; NP = 1772; lmax = 10; e = e0; }
    else { e = e0 - 168*1772; if (e >= 168*288) return; drk = drk3; DK = DK3; S = S_L5; NP = 288; lmax = 5; }
    int n = e / NP, idx = e % NP;
    if (idx >= S) { DK[e] = 0.f; return; }
    int l = 0; while (l < lmax && idx >= loff(l+1)) ++l;
    int j = idx - loff(l), d = 2*l+1;
    int iu = j/d, im = j%d;
    int u = iu - l, m = im - l;
    int i3 = n/24, k3 = n%8;
    double alpha = (double)i3*(2.0*PI_D/7.0);
    double gamma = (-2.0*PI_D + (double)k3*(4.0*PI_D/7.0)) - alpha;
    const float* drb = drk + (size_t)n*S + loff(l);
    double d_um   = drb[iu*d+im];
    double d_umn  = drb[iu*d + (d-1-im)];
    double d_unm  = drb[(d-1-iu)*d + im];
    double d_unmn = drb[(d-1-iu)*d + (d-1-im)];
    double cA = cos((double)u*alpha), sA = sin((double)u*alpha);
    double cG = cos((double)m*gamma), sG = sin((double)m*gamma);
    DK[e] = (float)(cA*(cG*d_um - sG*d_umn) + sA*(cG*d_unm - sG*d_unmn));
  } else {
    // ---- coeff[b][c] with inline FS2 (per-block trig caches) ----
    int c = b - 1463;
    int l = isqrt_dev(c);
    int u = c - l*l - l;
    int cneg = c - 2*u;
    if (tid < 60) {
      double alpha = (double)tid*(2.0*PI_D/60.0);
      double beta  = ((double)tid + 0.5)*(PI_D/60.0);
      cu[tid]  = (float)cos((double)u*alpha);
      su[tid]  = (float)sin((double)u*alpha);
      sbq[tid] = (float)(sin(beta)*PI_D/(2.0*60.0*60.0));
    }
    __syncthreads();
    float acc[8] = {};
    for (int k = tid; k < 3600; k += 256) {
      int ia = k / 60, ib2 = k % 60;
      double val = (double)cu[ia]*(double)drc60[ib2*441 + c] + (double)su[ia]*(double)drc60[ib2*441 + cneg];
      float w = (float)(val) * sbq[ib2];
#pragma unroll
      for (int bb = 0; bb < 8; ++bb) acc[bb] += w * x[bb*3600 + k];
    }
#pragma unroll
    for (int bb = 0; bb < 8; ++bb) red[bb*256 + tid] = acc[bb];
    __syncthreads();
    for (int s = 128; s > 0; s >>= 1) {
      if (tid < s) {
#pragma unroll
        for (int bb = 0; bb < 8; ++bb) red[bb*256 + tid] += red[bb*256 + tid + s];
      }
      __syncthreads();
    }
    if (tid < 8) coeff[tid*441 + c] = red[tid*256];
  }
}

// ping-pong LDS 64x64 GEMM body, K-step 16, f4 staging, packed-psi epilogue.
__device__ __forceinline__ void gemm_body(const float* __restrict__ A, const float* __restrict__ B,
                                          const unsigned* __restrict__ lut, float* __restrict__ C,
                                          int M, int N, int NP, int K, int FO, int tm, int tn, float alpha,
                                          float (*As)[16][68], float (*Bs)[16][68], int tid) {
  int ty = tid/16, tx = tid%16;
  int arr = tid>>2, akq = (tid&3)*4;
  int bkk = tid>>4, bcq = (tid&15)*4;
  const float* Arow = A + (size_t)(tm + arr)*K;
  const f4 FZ = 0.f;
  float acc[4][4] = {};
  f4 ra, rb;
#define LOADC(k0)                                                        \
  if ((k0) + 16 <= K) {                                                  \
    ra = *(const f4*)&Arow[(k0) + akq];                                  \
    rb = *(const f4*)&B[(size_t)((k0) + bkk)*NP + tn + bcq];             \
  } else {                                                               \
    _Pragma("unroll")                                                    \
    for (int jj = 0; jj < 4; ++jj) {                                     \
      int k = (k0) + akq + jj;                                           \
      ra[jj] = (k < K) ? Arow[k] : 0.f;                                  \
    }                                                                    \
    int k2 = (k0) + bkk;                                                 \
    rb = (k2 < K) ? *(const f4*)&B[(size_t)k2*NP + tn + bcq] : FZ;       \
  }
#define STOREC(b)                                                        \
  {                                                                      \
    _Pragma("unroll")                                                    \
    for (int jj = 0; jj < 4; ++jj) As[b][akq+jj][arr] = ra[jj];          \
    *(f4*)&Bs[b][bkk][bcq] = rb;                                         \
  }
  LOADC(0);
  STOREC(0);
  __syncthreads();
  int cur = 0;
  for (int k0 = 0; k0 < K; k0 += 16) {
    bool nxt = (k0 + 16) < K;
    if (nxt) { LOADC(k0 + 16); }
#pragma unroll
    for (int kk = 0; kk < 16; ++kk) {
      f4 av = *(const f4*)&As[cur][kk][ty*4];
      f4 bv = *(const f4*)&Bs[cur][kk][tx*4];
#pragma unroll
      for (int q = 0; q < 4; ++q)
#pragma unroll
        for (int r2 = 0; r2 < 4; ++r2) acc[q][r2] += av[q]*bv[r2];
    }
    if (nxt) { STOREC(cur ^ 1); __syncthreads(); cur ^= 1; }
  }
#undef LOADC
#undef STOREC
  for (int q = 0; q < 4; ++q) {
    int r = tm + ty*4 + q; if (r >= M) continue;
    int i = r / FO, o = r - i*FO;
    for (int r2 = 0; r2 < 4; ++r2) {
      int c = tn + tx*4 + r2; if (c >= N) continue;
      unsigned e = lut[c];
      int l = e & 255, u = (e>>8)&255, v = (e>>16)&255;
      int d = 2*l+1;
      C[(size_t)M*loff(l) + (size_t)(i*d+u)*(FO*d) + o*d + v] = alpha*acc[q][r2];
    }
  }
}

// RANK-1 synthesis body (L=20, NG=20, F=64, BS=256), batched 2f x 2b, shared carved from shbuf.
__device__ void syn1b_body(const float* __restrict__ psi1, const float* __restrict__ coeff,
                           const float* __restrict__ drg,
                           const float* __restrict__ gtck, const float* __restrict__ gtsk,
                           float* __restrict__ fw, int ib, int f0, int b0, int tid,
                           float* PF, float* Q1F, float* Q2F, float* Q3F,
                           float* uni, float* tck, float* tsk) {
  constexpr int L = 20, NG = 20, F = 64, BS = 256;
  constexpr int LH = L+1;
  constexpr int LH2 = LH*LH;
  constexpr int S = S_L20;
  constexpr int IGB = 4;
  constexpr int NGB = NG / IGB;
  float* psi_s  = uni;
  float* coef_s = uni + 2*C_L20;
  float* Rc = uni;
  float* Rs = uni + LH*NG;
  for (int t = tid; t < C_L20; t += BS) {
    psi_s[t]          = psi1[f0*C_L20 + t];
    psi_s[C_L20 + t]  = psi1[(f0+1)*C_L20 + t];
    coef_s[t]         = coeff[b0*C_L20 + t];
    coef_s[C_L20 + t] = coeff[(b0+1)*C_L20 + t];
  }
  for (int t = tid; t < LH*NG; t += BS) { tck[t] = gtck[t]; tsk[t] = gtsk[t]; }
  __syncthreads();
  const float* drb = drg + (size_t)ib*S;
  for (int t = tid; t < LH2; t += BS) {
    int i = t / LH, j = t % LH;
    int lmin = max(i, j);
    float P[4] = {}, Q1[4] = {}, Q2[4] = {}, Q3[4] = {};
    int d = 2*lmin+1;
    int j2 = 2*j;
    int drip = loff(lmin) + (lmin+i)*d + (lmin-j);
    int drim = loff(lmin) + (lmin-i)*d + (lmin-j);
    int hA = lmin*lmin + lmin + i;
    int hB = lmin*lmin + lmin - i;
    int hM = lmin*lmin + lmin - j;
    int hMp = lmin*lmin + lmin + j;
    for (int l = lmin; l <= L; ++l) {
      float ap_ = drb[drip], app = drb[drip + j2];
      float am_ = 0.f, amp = 0.f;
      if (i > 0) { am_ = drb[drim]; amp = drb[drim + j2]; }
      float eP[2], oP[2], eM[2], oM[2];
#pragma unroll
      for (int cb = 0; cb < 2; ++cb) {
        float hm = coef_s[cb*C_L20 + hM], hmn = coef_s[cb*C_L20 + hMp];
        eP[cb] = ap_*hm + app*hmn;  oP[cb] = app*hm - ap_*hmn;
        eM[cb] = am_*hm + amp*hmn;  oM[cb] = amp*hm - am_*hmn;
      }
#pragma unroll
      for (int cf = 0; cf < 2; ++cf) {
        float ha = psi_s[cf*C_L20 + hA], hb = psi_s[cf*C_L20 + hB];
#pragma unroll
        for (int cb = 0; cb < 2; ++cb) {
          int cs = cb*2 + cf;
          P[cs]  += ha*eP[cb] + hb*eM[cb];
          Q1[cs] += ha*oP[cb] + hb*oM[cb];
          Q2[cs] += hb*eP[cb] - ha*eM[cb];
          Q3[cs] += hb*oP[cb] - ha*oM[cb];
        }
      }
      drip += d*d + d + 2*(l+i) + 3;
      drim += d*d + d + 2*(l-i) + 3;
      int hstep = d + 1;
      hA += hstep; hB += hstep; hM += hstep; hMp += hstep;
      d += 2;
    }
    if (j == 0) {
#pragma unroll
      for (int cs = 0; cs < 4; ++cs) { P[cs] *= 0.5f; Q2[cs] *= 0.5f; }
    }
#pragma unroll
    for (int cs = 0; cs < 4; ++cs) {
      PF[cs*LH2 + t] = P[cs]; Q1F[cs*LH2 + t] = Q1[cs];
      Q2F[cs*LH2 + t] = Q2[cs]; Q3F[cs*LH2 + t] = Q3[cs];
    }
  }
  __syncthreads();
  double beta = ((double)ib + 0.5) * (PI_D / (double)NG);
  float qwv = (float)(sin(beta) * PI_D / (2.0*(double)NG*(double)NG*(double)NG));
  for (int cs = 0; cs < 4; ++cs) {
    int cf = cs & 1, cb = cs >> 1;
    for (int t = tid; t < LH*NGB; t += BS) {
      int i = t / NGB, ig0 = (t % NGB)*IGB;
      f4 rc = 0.f, rs = 0.f;
      const float* Pr  = PF  + cs*LH2 + i*LH;
      const float* Q1r = Q1F + cs*LH2 + i*LH;
      const float* Q2r = Q2F + cs*LH2 + i*LH;
      const float* Q3r = Q3F + cs*LH2 + i*LH;
      for (int k = 0; k <= L; ++k) {
        float p = Pr[k], q1 = Q1r[k], q2 = Q2r[k], q3 = Q3r[k];
        f4 c = *(const f4*)(tck + k*NG + ig0);
        f4 s = *(const f4*)(tsk + k*NG + ig0);
        rc += c*p + s*q1;
        rs += c*q2 + s*q3;
      }
      *(f4*)(Rc + i*NG + ig0) = rc;
      *(f4*)(Rs + i*NG + ig0) = rs;
    }
    __syncthreads();
    size_t obase = (((size_t)(b0+cb)*F + (f0+cf))*NG + ib)*(size_t)(NG*NG);
    for (int t = tid; t < NG*NGB; t += BS) {
      int ia = t / NGB, ig0 = (t % NGB)*IGB;
      f4 acc = 0.f;
      for (int k = 0; k <= L; ++k) {
        float ca = tck[k*NG + ia], sa = tsk[k*NG + ia];
        f4 rc = *(const f4*)(Rc + k*NG + ig0);
        f4 rs = *(const f4*)(Rs + k*NG + ig0);
        acc += ca*rc - sa*rs;
      }
      f4 res;
#pragma unroll
      for (int jj = 0; jj < 4; ++jj) res[jj] = fmaxf(acc[jj], 0.0f) * qwv;
      *(f4*)(fw + obase + ia*NG + ig0) = res;
    }
    __syncthreads();
  }
}

// both psi GEMMs + act1 synthesis in ONE launch (independent work, time-shared chip)
__global__ __launch_bounds__(256) void k_gs(const float* __restrict__ A1, const float* __restrict__ B1,
                                            const unsigned* __restrict__ lut1, float* __restrict__ C1,
                                            int M1, int N1, int NP1, int FO1,
                                            const float* __restrict__ A2, const float* __restrict__ B2,
                                            const unsigned* __restrict__ lut2, float* __restrict__ C2,
                                            int M2, int N2, int NP2, int FO2,
                                            int K, int nbx1, int nb1, int nbx2, int nb12, float alpha,
                                            const float* __restrict__ psi1, const float* __restrict__ coeff,
                                            const float* __restrict__ dr20g1,
                                            const float* __restrict__ t1ck, const float* __restrict__ t1sk,
                                            float* __restrict__ fwbuf) {
  __shared__ __align__(16) float shbuf[9664];
  int bid = blockIdx.x, tid = threadIdx.x;
  if (bid < nb1) {
    int tm = (bid % nbx1)*64, tn = (bid / nbx1)*64;
    gemm_body(A1, B1, lut1, C1, M1, N1, NP1, K, FO1, tm, tn, alpha,
              (float(*)[16][68])shbuf, (float(*)[16][68])(shbuf + 2176), tid);
  } else if (bid < nb12) {
    int b2 = bid - nb1;
    int tm = (b2 % nbx2)*64, tn = (b2 / nbx2)*64;
    gemm_body(A2, B2, lut2, C2, M2, N2, NP2, K, FO2, tm, tn, alpha,
              (float(*)[16][68])shbuf, (float(*)[16][68])(shbuf + 2176), tid);
  } else {
    int b2 = bid - nb12;
    int ib = b2 % 20;
    int r = b2 / 20;
    int f0 = (r % 32)*2;
    int b0 = (r / 32)*2;
    syn1b_body(psi1, coeff, dr20g1, t1ck, t1sk, fwbuf, ib, f0, b0, tid,
               shbuf, shbuf + 1764, shbuf + 3528, shbuf + 5292,
               shbuf + 7056, shbuf + 8820, shbuf + 9240);
  }
}

// fused ana-reduce + pack: hA[8*FI*loff(l) + (b*d+m)*(FI*d) + i*d+u] = sum_c part[c][bi][s]
__global__ __launch_bounds__(256) void k_anapack(const float* __restrict__ part, const unsigned* __restrict__ lut,
                                                 float* __restrict__ hA, int FI, int S, int nch) {
  int e = blockIdx.x*256 + threadIdx.x;
  int total = 8*FI*S;
  if (e >= total) return;
  int bi = e / S, s = e - bi*S;
  float a = 0.f;
  for (int c = 0; c < nch; ++c) a += part[(size_t)c*total + e];
  unsigned u3 = lut[s];
  int l = u3 & 255, u = (u3>>8)&255, m = (u3>>16)&255;
  int d = 2*l+1;
  int b = bi / FI, i = bi - b*FI;
  hA[(size_t)8*FI*loff(l) + (size_t)(b*d+m)*(FI*d) + i*d + u] = a;
}

// split-K packed per-l block linear, ping-pong LDS + f4 staging. Writes scaled partials.
__global__ __launch_bounds__(256) void k_linsk(const float* __restrict__ hA, const float* __restrict__ psiP,
                                               float* __restrict__ part, int FI, int FO, int S,
                                               int maxNT, int KC) {
  int l = blockIdx.z;
  int d = 2*l+1, off = loff(l);
  int Ml = 8*d, Nl = FO*d, Kl = FI*d;
  int tm = blockIdx.x*64;
  int tn = ((int)blockIdx.y % maxNT)*64;
  int kci = (int)blockIdx.y / maxNT;
  int k0s = kci*KC;
  if (tm >= Ml || tn >= Nl || k0s >= Kl) return;
  int k1s = min(Kl, k0s + KC);
  float alpha = 1.0f/sqrtf((float)(FI*d));
  const float* Ab = hA + (size_t)8*FI*off;
  const float* Bb = psiP + (size_t)FI*FO*off;
  __shared__ __align__(16) float As[2][16][68], Bs[2][16][68];
  int tid = threadIdx.x, ty = tid/16, tx = tid%16;
  int arr = tid>>2, akq = (tid&3)*4;
  int bkk = tid>>4, bcq = (tid&15)*4;
  bool aok = (tm + arr) < Ml;
  const float* Arow = Ab + (size_t)(tm + arr)*Kl;
  const f4 FZ = 0.f;
  float acc[4][4] = {};
  f4 ra, rb;
#define LOADL(k0)                                                        \
  {                                                                      \
    ra = aok ? *(const f4*)&Arow[(k0) + akq] : FZ;                       \
    rb = *(const f4*)&Bb[(size_t)((k0) + bkk)*Nl + tn + bcq];            \
  }
#define STOREL(b)                                                        \
  {                                                                      \
    _Pragma("unroll")                                                    \
    for (int jj = 0; jj < 4; ++jj) As[b][akq+jj][arr] = ra[jj];          \
    *(f4*)&Bs[b][bkk][bcq] = rb;                                         \
  }
  LOADL(k0s);
  STOREL(0);
  __syncthreads();
  int cur = 0;
  for (int k0 = k0s; k0 < k1s; k0 += 16) {
    bool nxt = (k0 + 16) < k1s;
    if (nxt) { LOADL(k0 + 16); }
#pragma unroll
    for (int kk = 0; kk < 16; ++kk) {
      f4 av = *(const f4*)&As[cur][kk][ty*4];
      f4 bv = *(const f4*)&Bs[cur][kk][tx*4];
#pragma unroll
      for (int q = 0; q < 4; ++q)
#pragma unroll
        for (int r2 = 0; r2 < 4; ++r2) acc[q][r2] += av[q]*bv[r2];
    }
    if (nxt) { STOREL(cur ^ 1); __syncthreads(); cur ^= 1; }
  }
#undef LOADL
#undef STOREL
  size_t pbase = (size_t)kci * (size_t)8*FO*S;
  for (int q = 0; q < 4; ++q) {
    int r = tm + ty*4 + q; if (r >= Ml) continue;
    int b = r / d, m = r - b*d;
    for (int r2 = 0; r2 < 4; ++r2) {
      int c = tn + tx*4 + r2; if (c >= Nl) continue;
      int o = c / d, v = c - o*d;
      part[pbase + (size_t)(b*FO + o)*S + off + v*d + m] = alpha*acc[q][r2];
    }
  }
}

// non-rank1 synthesis, u-PAIR-FOLDED stage A, with INLINE split-K partial sum on load.
template<int L, int NG, int F, int BS>
__global__ __launch_bounds__(BS) void k_syn(const float* __restrict__ part, int thr1, int thr2, int total,
                                            const float* __restrict__ drg,
                                            const float* __restrict__ gtck, const float* __restrict__ gtsk,
                                            float* __restrict__ fw) {
  constexpr int LH = L+1;
  constexpr int LH2 = LH*LH;
  constexpr int S = (L+1)*(2*L+1)*(2*L+3)/3;
  constexpr int RCSZ = LH*NG;
  constexpr int UNI = (S > 2*RCSZ) ? S : 2*RCSZ;
  constexpr int IGB = (NG % 4 == 0) ? 4 : 2;
  constexpr int NGB = NG / IGB;
  using VecT = typename VW<IGB>::T;
  __shared__ float PF[LH2], Q1F[LH2], Q2F[LH2], Q3F[LH2];
  __shared__ __align__(16) float uni[UNI];
  __shared__ __align__(16) float tck[LH*NG], tsk[LH*NG];
  float* hrow = uni;
  float* Rc = uni;
  float* Rs = uni + RCSZ;
  int ib = blockIdx.x, f = blockIdx.y, b = blockIdx.z;
  int tid = threadIdx.x;
  for (int t = tid; t < S; t += BS) {
    size_t e = ((size_t)b*F + f)*S + t;
    float a = part[e];
    if (t >= thr1) a += part[(size_t)total + e];
    if (t >= thr2) a += part[2*(size_t)total + e];
    hrow[t] = a;
  }
  for (int t = tid; t < LH*NG; t += BS) { tck[t] = gtck[t]; tsk[t] = gtsk[t]; }
  __syncthreads();
  const float* drb = drg + (size_t)ib*S;
  for (int t = tid; t < LH2; t += BS) {
    int i = t / LH, j = t % LH;
    int lmin = max(i, j);
    float P = 0.f, Q1 = 0.f, Q2 = 0.f, Q3 = 0.f;
    int d = 2*lmin+1;
    int j2 = 2*j;
    int drip = loff(lmin) + (lmin+i)*d + (lmin-j);
    int drim = loff(lmin) + (lmin-i)*d + (lmin-j);
    for (int l = lmin; l <= L; ++l) {
      float ap_ = drb[drip], app = drb[drip + j2];
      float am_ = 0.f, amp = 0.f;
      if (i > 0) { am_ = drb[drim]; amp = drb[drim + j2]; }
      float hp1 = hrow[drip], hp2 = hrow[drip + j2];
      float hm1 = hrow[drim], hm2 = hrow[drim + j2];
      P  += ap_*hp1 + app*hp2 + am_*hm1 + amp*hm2;
      Q1 += app*hp1 - ap_*hp2 + amp*hm1 - am_*hm2;
      Q2 += ap_*hm1 + app*hm2 - am_*hp1 - amp*hp2;
      Q3 += app*hm1 - ap_*hm2 - amp*hp1 + am_*hp2;
      drip += d*d + d + 2*(l+i) + 3;
      drim += d*d + d + 2*(l-i) + 3;
      d += 2;
    }
    if (j == 0) { P *= 0.5f; Q2 *= 0.5f; }
    PF[t] = P; Q1F[t] = Q1; Q2F[t] = Q2; Q3F[t] = Q3;
  }
  __syncthreads();
  for (int t = tid; t < LH*NGB; t += BS) {
    int i = t / NGB, ig0 = (t % NGB)*IGB;
    VecT rc = 0.f, rs = 0.f;
    const float* Pr  = PF  + i*LH;
    const float* Q1r = Q1F + i*LH;
    const float* Q2r = Q2F + i*LH;
    const float* Q3r = Q3F + i*LH;
    for (int k = 0; k <= L; ++k) {
      float p = Pr[k], q1 = Q1r[k], q2 = Q2r[k], q3 = Q3r[k];
      VecT c = *(const VecT*)(tck + k*NG + ig0);
      VecT s = *(const VecT*)(tsk + k*NG + ig0);
      rc += c*p + s*q1;
      rs += c*q2 + s*q3;
    }
    *(VecT*)(Rc + i*NG + ig0) = rc;
    *(VecT*)(Rs + i*NG + ig0) = rs;
  }
  __syncthreads();
  double beta = ((double)ib + 0.5) * (PI_D / (double)NG);
  float qwv = (float)(sin(beta) * PI_D / (2.0*(double)NG*(double)NG*(double)NG));
  size_t obase = (((size_t)b*F + f)*NG + ib)*(size_t)(NG*NG);
  for (int t = tid; t < NG*NGB; t += BS) {
    int ia = t / NGB, ig0 = (t % NGB)*IGB;
    VecT acc = 0.f;
    for (int k = 0; k <= L; ++k) {
      float ca = tck[k*NG + ia], sa = tsk[k*NG + ia];
      VecT rc = *(const VecT*)(Rc + k*NG + ig0);
      VecT rs = *(const VecT*)(Rs + k*NG + ig0);
      acc += ca*rc - sa*rs;
    }
    VecT res;
#pragma unroll
    for (int jj = 0; jj < IGB; ++jj) res[jj] = fmaxf(acc[jj], 0.0f) * qwv;
    *(VecT*)(fw + obase + ia*NG + ig0) = res;
  }
}

// factorized SO(3) grid analysis to lmax LO, ib-chunked, PARITY-FOLDED on all
// four DFT axes (output mu_u/mu_m and inner ia/ig). hpart[ibc][b][f][SO]
template<int LO, int NG, int F, int IBN, int BS>
__global__ __launch_bounds__(BS) void k_ana(const float* __restrict__ fw, const float* __restrict__ drg,
                                            const float* __restrict__ gtck, const float* __restrict__ gtsk,
                                            float* __restrict__ hpart) {
  constexpr int LH = LO+1;
  constexpr int LHP = (LH+3)&~3;
  constexpr int NH = NG/2;               // NG even (20,10,6)
  constexpr int SO = (LO+1)*(2*LO+1)*(2*LO+3)/3;
  constexpr int ME = (SO+BS-1)/BS;
  __shared__ float fws[NG*NG];
  __shared__ float fe[(NH+1)*NG], fo[(NH-1)*NG];
  __shared__ float drs[SO];
  __shared__ float FcF[LH*NG], FsF[LH*NG];
  __shared__ float FcFe[LH*(NH+1)], FcFo[LH*(NH-1)];
  __shared__ float FsFe[LH*(NH+1)], FsFo[LH*(NH-1)];
  __shared__ float Gcc[LH*LHP], Gcs[LH*LHP], Gsc[LH*LHP], Gss[LH*LHP];
  __shared__ float tc[LH*NG], ts[LH*NG];  // k-major, rows 0..LO
  __shared__ unsigned lut[SO];
  int f = blockIdx.x, b = blockIdx.y, ibc = blockIdx.z, tid = threadIdx.x;
  for (int t = tid; t < LH*NG; t += BS) { tc[t] = gtck[t]; ts[t] = gtsk[t]; }
  for (int t = tid; t < SO; t += BS) {
    int l = 0; while (l < LO && t >= loff(l+1)) ++l;
    int j = t - loff(l), d = 2*l+1;
    int iu = j/d, im = j - iu*d;
    lut[t] = (unsigned)l | ((unsigned)iu<<8) | ((unsigned)im<<16);
  }
  float rf[ME];
#pragma unroll
  for (int e = 0; e < ME; ++e) rf[e] = 0.f;
  __syncthreads();
  int ib0 = ibc*IBN, ib1 = min(NG, ib0 + IBN);
  for (int ib = ib0; ib < ib1; ++ib) {
    size_t base = (((size_t)b*F + f)*NG + ib)*(size_t)(NG*NG);
    for (int t = tid; t < NG*NG; t += BS) fws[t] = fw[base + t];
    for (int t = tid; t < SO; t += BS) drs[t] = drg[(size_t)ib*SO + t];
    __syncthreads();
    // fold fw over ia (cos even / sin odd around ia -> NG-ia)
    for (int t = tid; t < (NH+1)*NG; t += BS) {
      int ia = t / NG, ig = t % NG;
      float v = fws[ia*NG + ig];
      if (ia > 0 && ia < NH) v += fws[(NG-ia)*NG + ig];
      fe[t] = v;
    }
    for (int t = tid; t < (NH-1)*NG; t += BS) {
      int ia = t / NG + 1, ig = t % NG;
      fo[t] = fws[ia*NG + ig] - fws[(NG-ia)*NG + ig];
    }
    __syncthreads();
    // stage 1 (folded): FcF[k][ig], FsF[k][ig] for k = |mu_u| = 0..LO
    for (int t = tid; t < LH*NG; t += BS) {
      int k = t / NG, ig = t % NG;
      float fc = 0.f, fs = 0.f;
      for (int ia = 0; ia <= NH; ++ia) fc += tc[k*NG + ia]*fe[ia*NG + ig];
      for (int ia = 1; ia < NH;  ++ia) fs += ts[k*NG + ia]*fo[(ia-1)*NG + ig];
      FcF[t] = fc; FsF[t] = fs;
    }
    __syncthreads();
    // fold F over ig
    for (int t = tid; t < LH*(NH+1); t += BS) {
      int k = t / (NH+1), jg = t % (NH+1);
      float c = FcF[k*NG + jg], s = FsF[k*NG + jg];
      if (jg > 0 && jg < NH) { c += FcF[k*NG + NG - jg]; s += FsF[k*NG + NG - jg]; }
      FcFe[t] = c; FsFe[t] = s;
    }
    for (int t = tid; t < LH*(NH-1); t += BS) {
      int k = t / (NH-1), jg = t % (NH-1) + 1;
      FcFo[t] = FcF[k*NG + jg] - FcF[k*NG + NG - jg];
      FsFo[t] = FsF[k*NG + jg] - FsF[k*NG + NG - jg];
    }
    __syncthreads();
    // stage 2 (folded): G**[k][km] for km = |mu_m| = 0..LO
    for (int t = tid; t < LH*LH; t += BS) {
      int k = t / LH, km = t % LH;
      float gcc = 0.f, gcs = 0.f, gsc = 0.f, gss = 0.f;
      for (int jg = 0; jg <= NH; ++jg) {
        float tcv = tc[km*NG + jg];
        gcc += tcv*FcFe[k*(NH+1) + jg];
        gsc += tcv*FsFe[k*(NH+1) + jg];
      }
      for (int jg = 1; jg < NH; ++jg) {
        float tsv = ts[km*NG + jg];
        gcs += tsv*FcFo[k*(NH-1) + jg - 1];
        gss += tsv*FsFo[k*(NH-1) + jg - 1];
      }
      Gcc[k*LHP + km] = gcc; Gcs[k*LHP + km] = gcs;
      Gsc[k*LHP + km] = gsc; Gss[k*LHP + km] = gss;
    }
    __syncthreads();
    // stage 3: per-element accumulate with sign reconstruction
#pragma unroll
    for (int e = 0; e < ME; ++e) {
      int t = tid + e*BS;
      if (t < SO) {
        unsigned u3 = lut[t];
        int l = u3 & 255, iu = (u3>>8)&255, im = (u3>>16)&255;
        int d = 2*l+1;
        int bidx = loff(l) + iu*d + im;
        int ru = (d-1-2*iu)*d, rm = d-1-2*im;
        int du_ = iu - l, dm_ = im - l;
        int ku = (du_ < 0) ? -du_ : du_;
        int km = (dm_ < 0) ? -dm_ : dm_;
        int gi = ku*LHP + km;
        float d1 = drs[bidx], d2 = drs[bidx+rm], d3 = drs[bidx+ru], d4 = drs[bidx+ru+rm];
        float g1 = Gcc[gi], g2 = Gcs[gi], g3 = Gsc[gi], g4 = Gss[gi];
        if (dm_ < 0) { g2 = -g2; g4 = -g4; }
        if (du_ < 0) { g3 = -g3; g4 = -g4; }
        rf[e] += g1*d1 - g2*d2 + g3*d3 - g4*d4;
      }
    }
    __syncthreads();
  }
  size_t obase = (size_t)ibc*((size_t)8*F*SO) + ((size_t)b*F + f)*SO;
#pragma unroll
  for (int e = 0; e < ME; ++e) {
    int t = tid + e*BS;
    if (t < SO) hpart[obase + t] = rf[e];
  }
}

// final two FC layers. one block, 1024 threads.
__global__ __launch_bounds__(1024) void k_fc(const float* __restrict__ h4, const float* __restrict__ w1,
                                             const float* __restrict__ b1, const float* __restrict__ w2,
                                             const float* __restrict__ b2, float* __restrict__ out) {
  __shared__ float t1[1024];
  int tid = threadIdx.x;
  {
    int b = tid >> 7, j = tid & 127;
    float a = b1[j];
    const float* hr = h4 + b*256;
    for (int k = 0; k < 256; ++k) a += hr[k]*w1[k*128 + j];
    t1[tid] = fmaxf(a, 0.f);
  }
  __syncthreads();
  if (tid < 80) {
    int b = tid / 10, j = tid % 10;
    float a = b2[j];
    for (int k = 0; k < 128; ++k) a += t1[b*128 + k]*w2[k*10 + j];
    out[b*10 + j] = a;
  }
}

extern "C" void kernel_launch(void* const* d_in, const int* in_sizes, int n_in,
                              void* d_out, int out_size, void* d_ws, size_t ws_size,
                              hipStream_t stream) {
  const float* x    = (const float*)d_in[0];
  const float* w1   = (const float*)d_in[1];
  const float* w2   = (const float*)d_in[2];
  const float* w3   = (const float*)d_in[3];
  const float* fcw1 = (const float*)d_in[4];
  const float* fcb1 = (const float*)d_in[5];
  const float* fcw2 = (const float*)d_in[6];
  const float* fcb2 = (const float*)d_in[7];
  float* out = (float*)d_out;

  float* base = (float*)d_ws;
  size_t off = 0;
  auto alloc = [&](size_t n) -> float* { float* p = base + off; off += (n + 63) & ~(size_t)63; return p; };

  float* drc60  = alloc((size_t)60*441);
  float* drc24  = alloc((size_t)24*441);
  float* psi1   = alloc((size_t)64*441);
  float* coeff  = alloc((size_t)8*441);
  float* drK2   = alloc((size_t)168*S_L10);
  float* drK3   = alloc((size_t)168*S_L5);
  float* dk2    = alloc((size_t)168*1772 + 64);   // padded stride 1772
  float* dk3    = alloc((size_t)168*288 + 64);    // padded stride 288
  float* psi2P  = alloc((size_t)8192*S_L10);
  float* psi3P  = alloc((size_t)32768*S_L5);
  float* dr20g1 = alloc((size_t)20*S_L20);
  float* dr10g1 = alloc((size_t)20*S_L10);
  float* dr10g2 = alloc((size_t)10*S_L10);
  float* dr5g2  = alloc((size_t)10*S_L5);
  float* dr5g3  = alloc((size_t)6*S_L5);
  float* dr0g3  = alloc(6);
  float* t1ck   = alloc((size_t)21*20);
  float* t1sk   = alloc((size_t)21*20);
  float* t2ck   = alloc((size_t)11*10);
  float* t2sk   = alloc((size_t)11*10);
  float* t3ck   = alloc((size_t)6*6);
  float* t3sk   = alloc((size_t)6*6);
  float* lut10  = alloc((size_t)S_L10);   // unsigned, same size as float
  float* lut5   = alloc((size_t)S_L5);
  float* fwbuf  = alloc((size_t)8*64*8000);         // aliased: fw1b / fw2b / fw3b
  float* scr    = alloc((size_t)3*8*128*S_L10);     // aliased: hp1 / part2 / hp2 / part3
  float* hA2    = alloc((size_t)8*64*S_L10);
  float* hA3    = alloc((size_t)8*128*S_L5);
  float* h4     = alloc((size_t)8*256);
  if (off * sizeof(float) > ws_size) return;

  const float inv_s168 = 0.07715167498104595f;  // 1/sqrt(168)
  const int KC = 512;

  // ---- ALL constant tables, two launches ----
  k_tables<<<dim3(942), 256, 0, stream>>>(dr20g1, drK2, dr10g1, dr10g2, drK3, dr5g2, dr5g3, dr0g3,
                                          drc60, drc24, t1ck, t1sk, t2ck, t2sk, t3ck, t3sk,
                                          (unsigned*)lut10, (unsigned*)lut5);
  k_tab2<<<dim3(1904), 256, 0, stream>>>(drc24, w1, psi1, drK2, dk2, drK3, dk3, drc60, x, coeff);
  // ---- both psi GEMMs + act1 synthesis in one launch (independent work) ----
  k_gs<<<dim3(3584 + 2560 + 2560), 256, 0, stream>>>(
      w2, dk2, (const unsigned*)lut10, psi2P, 8192,  S_L10, 1772, 128,
      w3, dk3, (const unsigned*)lut5,  psi3P, 32768, S_L5,  288,  256,
      168, 128, 3584, 512, 6144, inv_s168,
      psi1, coeff, dr20g1, t1ck, t1sk, fwbuf);

  // ---- act1 analysis ----
  k_ana<10,20,64,4,256><<<dim3(64,8,5),  256, 0, stream>>>(fwbuf, dr10g1, t1ck, t1sk, scr);
  // ---- fused ana-reduce + pack, then so3 linear 2 (partials summed inside syn2) ----
  k_anapack<<<dim3((8*64*S_L10+255)/256), 256, 0, stream>>>(scr, (const unsigned*)lut10, hA2, 64, S_L10, 5);
  k_linsk<<<dim3(3, 42*3, 11), 256, 0, stream>>>(hA2, psi2P, scr, 64, 128, S_L10, 42, KC);
  // ---- act2 (syn sums lin2 split-K partials inline: thr = loff(4)=84, loff(8)=680) ----
  k_syn<10,10,128,128><<<dim3(10,128,8), 128, 0, stream>>>(scr, 84, 680, 8*128*S_L10, dr10g2, t2ck, t2sk, fwbuf);
  k_ana<5,10,128,5,128><<<dim3(128,8,2),  128, 0, stream>>>(fwbuf, dr5g2, t2ck, t2sk, scr);
  // ---- fused ana-reduce + pack, then so3 linear 3 (partials summed inside syn3) ----
  k_anapack<<<dim3((8*128*S_L5+255)/256), 256, 0, stream>>>(scr, (const unsigned*)lut5, hA3, 128, S_L5, 2);
  k_linsk<<<dim3(2, 44*3, 6), 256, 0, stream>>>(hA3, psi3P, scr, 128, 256, S_L5, 44, KC);
  // ---- act3 (syn sums lin3 split-K partials inline: thr = loff(2)=10, loff(4)=84) ----
  k_syn<5,6,256,64><<<dim3(6,256,8), 64, 0, stream>>>(scr, 10, 84, 8*256*S_L5, dr5g3, t3ck, t3sk, fwbuf);
  k_ana<0,6,256,6,64><<<dim3(256,8,1), 64, 0, stream>>>(fwbuf, dr0g3, t3ck, t3sk, h4);
  // ---- FC head ----
  k_fc<<<dim3(1), 1024, 0, stream>>>(h4, fcw1, fcb1, fcw2, fcb2, out);
}